// Round 2
// baseline (321.793 us; speedup 1.0000x reference)
//
#include <hip/hip_runtime.h>
#include <hip/hip_bf16.h>

// B=2, S=2048, HID=1024, H=16, KVH=4, D=64, G=4
// qkv row stride 1536 (q:0..1023, k:1024..1279, v:1280..1535)

typedef short bfx8 __attribute__((ext_vector_type(8)));   // 8 bf16 (4 VGPRs)
typedef float fx4  __attribute__((ext_vector_type(4)));   // MFMA C/D

#define DEV __device__ __forceinline__

DEV void load_lds16(const void* g, void* l) {
  __builtin_amdgcn_global_load_lds(
      (const __attribute__((address_space(1))) unsigned int*)g,
      (__attribute__((address_space(3))) unsigned int*)l, 16, 0, 0);
}

DEV unsigned short f2bf(float f) {
  unsigned int x = __builtin_bit_cast(unsigned int, f);
  unsigned int r = (x + 0x7fffu + ((x >> 16) & 1u)) >> 16;
  return (unsigned short)r;
}
DEV float bf2f(unsigned short u) {
  unsigned int x = ((unsigned int)u) << 16;
  return __builtin_bit_cast(float, x);
}

// ---------------- conversions ----------------

__global__ __launch_bounds__(256) void cvt_x_kernel(const float* __restrict__ x,
                                                    unsigned short* __restrict__ out) {
  int i = (blockIdx.x * 256 + threadIdx.x) * 8;
  fx4 a = *(const fx4*)(x + i);
  fx4 b = *(const fx4*)(x + i + 4);
  bfx8 r;
  r[0] = (short)f2bf(a[0]); r[1] = (short)f2bf(a[1]);
  r[2] = (short)f2bf(a[2]); r[3] = (short)f2bf(a[3]);
  r[4] = (short)f2bf(b[0]); r[5] = (short)f2bf(b[1]);
  r[6] = (short)f2bf(b[2]); r[7] = (short)f2bf(b[3]);
  *(bfx8*)(out + i) = r;
}

// wqkvT[1536][1024]: rows 0..1023 = wq^T, 1024..1279 = wk^T, 1280..1535 = wv^T
__global__ __launch_bounds__(256) void build_wqkvT_kernel(const float* __restrict__ wq,
                                                          const float* __restrict__ wk,
                                                          const float* __restrict__ wv,
                                                          unsigned short* __restrict__ out) {
  int tid = blockIdx.x * 256 + threadIdx.x;   // 1536*1024
  int r = tid >> 10, c = tid & 1023;
  float v;
  if (r < 1024)      v = wq[(size_t)c * 1024 + r];
  else if (r < 1280) v = wk[(size_t)c * 256 + (r - 1024)];
  else               v = wv[(size_t)c * 256 + (r - 1280)];
  out[tid] = f2bf(v);
}

__global__ __launch_bounds__(256) void build_woT_kernel(const float* __restrict__ wo,
                                                        unsigned short* __restrict__ out) {
  int tid = blockIdx.x * 256 + threadIdx.x;   // 1024*1024
  int r = tid >> 10, c = tid & 1023;
  out[tid] = f2bf(wo[(size_t)c * 1024 + r]);
}

// ---------------- RoPE (in place on qkv cols 0..1279) ----------------

__global__ __launch_bounds__(256) void rope_kernel(unsigned short* __restrict__ qkv,
                                                   const float* __restrict__ ct,
                                                   const float* __restrict__ st) {
  int tid = blockIdx.x * 256 + threadIdx.x;   // 4096 * 640
  int row = tid / 640;
  int rem = tid - row * 640;
  int head = rem >> 5, d = rem & 31;          // head 0..19 (q heads then k heads), d 0..31
  int s = row & 2047;
  float c = ct[s * 64 + d], sn = st[s * 64 + d];
  unsigned short* p = qkv + (size_t)row * 1536 + head * 64 + d;
  float x0 = bf2f(p[0]);
  float x1 = bf2f(p[32]);
  p[0]  = f2bf(x0 * c - x1 * sn);
  p[32] = f2bf(x1 * c + x0 * sn);
}

// ---------------- GEMM: C[M][ldc] = A[M][K] * Bt[N][K]^T ----------------
// 128x128 tile, BK=32, 256 threads (4 waves, 2x2 of 64x64), m97-style.

template <bool OUT_BF16>
__global__ __launch_bounds__(256) void gemm_bt_kernel(const unsigned short* __restrict__ A,
                                                      const unsigned short* __restrict__ Bt,
                                                      void* __restrict__ Cp,
                                                      int M, int N, int K, int ldc) {
  __shared__ __align__(16) unsigned short As[128 * 32];
  __shared__ __align__(16) unsigned short Bs[128 * 32];
  const int t = threadIdx.x;
  const int l = t & 63;
  const int w = t >> 6;
  const int wm = (w >> 1) * 64, wn = (w & 1) * 64;
  const int bm = blockIdx.x, bn = blockIdx.y;
  fx4 acc[4][4] = {};

  const int ra = t >> 2;     // staging local row 0..63
  const int ca = t & 3;      // staging chunk 0..3 (8 bf16 each)

  for (int kt = 0; kt < K; kt += 32) {
    __syncthreads();
#pragma unroll
    for (int p = 0; p < 2; ++p) {
      int rr = ra + p * 64;
      int gca = ((ca ^ ((rr >> 1) & 3)) * 8);   // pre-swizzled global chunk
      load_lds16(A + (size_t)(bm * 128 + rr) * K + kt + gca, (char*)As + p * 4096 + t * 16);
      load_lds16(Bt + (size_t)(bn * 128 + rr) * K + kt + gca, (char*)Bs + p * 4096 + t * 16);
    }
    __syncthreads();

    bfx8 af[4], bfr[4];
#pragma unroll
    for (int mi = 0; mi < 4; ++mi) {
      int row = wm + mi * 16 + (l & 15);
      int ch = (l >> 4) ^ ((row >> 1) & 3);
      af[mi] = *(const bfx8*)(As + row * 32 + ch * 8);
      int rowb = wn + mi * 16 + (l & 15);
      int chb = (l >> 4) ^ ((rowb >> 1) & 3);
      bfr[mi] = *(const bfx8*)(Bs + rowb * 32 + chb * 8);
    }
#pragma unroll
    for (int mi = 0; mi < 4; ++mi)
#pragma unroll
      for (int ni = 0; ni < 4; ++ni)
        acc[mi][ni] = __builtin_amdgcn_mfma_f32_16x16x32_bf16(af[mi], bfr[ni], acc[mi][ni], 0, 0, 0);
  }

#pragma unroll
  for (int mi = 0; mi < 4; ++mi) {
    int row0 = bm * 128 + wm + mi * 16 + (l >> 4) * 4;
#pragma unroll
    for (int ni = 0; ni < 4; ++ni) {
      int col = bn * 128 + wn + ni * 16 + (l & 15);
#pragma unroll
      for (int r = 0; r < 4; ++r) {
        if (OUT_BF16)
          ((unsigned short*)Cp)[(size_t)(row0 + r) * ldc + col] = f2bf(acc[mi][ni][r]);
        else
          ((float*)Cp)[(size_t)(row0 + r) * ldc + col] = acc[mi][ni][r];
      }
    }
  }
}

// ---------------- flash attention (causal, GQA) ----------------
// grid (S/64, H, B), 256 threads = 4 waves; wave w owns q rows q0+16w..+15.

__global__ __launch_bounds__(256) void attn_kernel(const unsigned short* __restrict__ qkv,
                                                   unsigned short* __restrict__ out) {
  __shared__ __align__(16) unsigned short Klds[32 * 64];   // chunk-swizzled
  __shared__ __align__(16) unsigned short Vt[64 * 40];     // V^T, rows permuted d^((d>>3)&7)
  __shared__ __align__(16) unsigned short Plds[4][16 * 32];

  const int qb = blockIdx.x, h = blockIdx.y, b = blockIdx.z;
  const int kvh = h >> 2;
  const int t = threadIdx.x, w = t >> 6, l = t & 63;
  const int q0 = qb * 64;
  const unsigned short* base = qkv + (size_t)b * 2048 * 1536;

  const int qrow = q0 + w * 16 + (l & 15);
  const bfx8 qf0 = *(const bfx8*)(base + (size_t)qrow * 1536 + h * 64 + (l >> 4) * 8);
  const bfx8 qf1 = *(const bfx8*)(base + (size_t)qrow * 1536 + h * 64 + 32 + (l >> 4) * 8);

  fx4 o[4] = {};
  float mrow[4], lrow[4];
#pragma unroll
  for (int r = 0; r < 4; ++r) { mrow[r] = -1e30f; lrow[r] = 0.f; }

  const int nkb = 2 * qb + 2;
  for (int kb = 0; kb < nkb; ++kb) {
    const int j0 = kb * 32;
    __syncthreads();   // previous iter's LDS reads done before restaging
    {  // K stage: row j (128B = 8 chunks), global chunk pre-swizzled by j&7
      int j = t >> 3, c = t & 7;
      int gc = (c ^ (j & 7)) * 8;
      load_lds16(base + (size_t)(j0 + j) * 1536 + 1024 + kvh * 64 + gc, (char*)Klds + t * 16);
    }
    {  // V stage: reg-load row chunk, transpose into Vt with row permute
      int j = t >> 3, d0 = (t & 7) * 8;
      bfx8 vv = *(const bfx8*)(base + (size_t)(j0 + j) * 1536 + 1280 + kvh * 64 + d0);
#pragma unroll
      for (int ii = 0; ii < 8; ++ii) {
        int d = d0 + ii;
        int pr = d ^ ((d >> 3) & 7);
        Vt[pr * 40 + j] = (unsigned short)vv[ii];
      }
    }
    __syncthreads();

    // QK^T -> S[16q][32k] in C layout (col=key=l&15, row=(l>>4)*4+r)
    fx4 s[2] = {};
#pragma unroll
    for (int kk = 0; kk < 2; ++kk) {
#pragma unroll
      for (int dd = 0; dd < 2; ++dd) {
        int j = kk * 16 + (l & 15);
        int g = dd * 4 + (l >> 4);
        bfx8 kf = *(const bfx8*)((const char*)Klds + j * 128 + ((g ^ (j & 7)) * 16));
        s[kk] = __builtin_amdgcn_mfma_f32_16x16x32_bf16(dd == 0 ? qf0 : qf1, kf, s[kk], 0, 0, 0);
      }
    }

    // online softmax
#pragma unroll
    for (int r = 0; r < 4; ++r) {
      const int qg = q0 + w * 16 + (l >> 4) * 4 + r;
      float s0 = s[0][r] * 0.125f;
      float s1 = s[1][r] * 0.125f;
      if (j0 + (l & 15) > qg) s0 = -1e30f;
      if (j0 + 16 + (l & 15) > qg) s1 = -1e30f;
      float mx = fmaxf(s0, s1);
#pragma unroll
      for (int off = 1; off < 16; off <<= 1) mx = fmaxf(mx, __shfl_xor(mx, off, 64));
      float mnew = fmaxf(mrow[r], mx);
      float corr = __expf(mrow[r] - mnew);
      mrow[r] = mnew;
      float p0 = __expf(s0 - mnew);
      float p1 = __expf(s1 - mnew);
      float ps = p0 + p1;
#pragma unroll
      for (int off = 1; off < 16; off <<= 1) ps += __shfl_xor(ps, off, 64);
      lrow[r] = lrow[r] * corr + ps;
#pragma unroll
      for (int nt = 0; nt < 4; ++nt) o[nt][r] *= corr;
      int q = (l >> 4) * 4 + r;
      int k0 = l & 15, k1 = 16 + (l & 15);
      Plds[w][q * 32 + ((((k0 >> 3) ^ ((q >> 1) & 3)) << 3)) + (k0 & 7)] = f2bf(p0);
      Plds[w][q * 32 + ((((k1 >> 3) ^ ((q >> 1) & 3)) << 3)) + (k1 & 7)] = f2bf(p1);
    }

    // PV: A=P[16q][32k] (via LDS re-layout), B=V[32k][16d] from Vt
    {
      int q = l & 15;
      int ch = (l >> 4) ^ ((q >> 1) & 3);
      bfx8 pf = *(const bfx8*)(&Plds[w][q * 32 + ch * 8]);
#pragma unroll
      for (int nt = 0; nt < 4; ++nt) {
        int d = nt * 16 + (l & 15);
        int pr = d ^ ((d >> 3) & 7);
        bfx8 vf = *(const bfx8*)(&Vt[pr * 40 + (l >> 4) * 8]);
        o[nt] = __builtin_amdgcn_mfma_f32_16x16x32_bf16(pf, vf, o[nt], 0, 0, 0);
      }
    }
  }

#pragma unroll
  for (int nt = 0; nt < 4; ++nt) {
#pragma unroll
    for (int r = 0; r < 4; ++r) {
      int row = q0 + w * 16 + (l >> 4) * 4 + r;
      float val = o[nt][r] / lrow[r];
      out[((size_t)(b * 2048) + row) * 1024 + h * 64 + nt * 16 + (l & 15)] = f2bf(val);
    }
  }
}

// ---------------- launch ----------------

extern "C" void kernel_launch(void* const* d_in, const int* in_sizes, int n_in,
                              void* d_out, int out_size, void* d_ws, size_t ws_size,
                              hipStream_t stream) {
  const float* x    = (const float*)d_in[0];
  const float* cosb = (const float*)d_in[1];
  const float* sinb = (const float*)d_in[2];
  const float* wq   = (const float*)d_in[3];
  const float* wk   = (const float*)d_in[4];
  const float* wv   = (const float*)d_in[5];
  const float* wo   = (const float*)d_in[6];
  float* out = (float*)d_out;

  char* ws = (char*)d_ws;
  // xb aliases attn_out: xb dead after GEMM1 (before attn_kernel writes)
  unsigned short* xb    = (unsigned short*)ws;                 //  8,388,608 B
  unsigned short* attn  = (unsigned short*)ws;                 //  (alias)
  unsigned short* wqkvT = (unsigned short*)(ws + 8388608);     //  3,145,728 B
  unsigned short* woT   = (unsigned short*)(ws + 11534336);    //  2,097,152 B
  unsigned short* qkv   = (unsigned short*)(ws + 13631488);    // 12,582,912 B  (total 25 MiB)

  cvt_x_kernel<<<2048, 256, 0, stream>>>(x, xb);
  build_wqkvT_kernel<<<6144, 256, 0, stream>>>(wq, wk, wv, wqkvT);
  build_woT_kernel<<<4096, 256, 0, stream>>>(wo, woT);
  gemm_bt_kernel<true><<<dim3(32, 12), 256, 0, stream>>>(xb, wqkvT, qkv, 4096, 1536, 1024, 1536);
  rope_kernel<<<10240, 256, 0, stream>>>(qkv, cosb, sinb);
  attn_kernel<<<dim3(32, 16, 2), 256, 0, stream>>>(qkv, attn);
  gemm_bt_kernel<false><<<dim3(32, 8), 256, 0, stream>>>(attn, woT, out, 4096, 1024, 1024, 1024);
}

// Round 3
// 231.188 us; speedup vs baseline: 1.3919x; 1.3919x over previous
//
#include <hip/hip_runtime.h>
#include <hip/hip_bf16.h>

// B=2, S=2048, HID=1024, H=16, KVH=4, D=64, G=4
// qkv row stride 1536 (q:0..1023, k:1024..1279, v:1280..1535)

typedef short bfx8 __attribute__((ext_vector_type(8)));   // 8 bf16 (4 VGPRs)
typedef float fx4  __attribute__((ext_vector_type(4)));   // MFMA C/D 16x16
typedef float fx16 __attribute__((ext_vector_type(16)));  // MFMA C/D 32x32
typedef unsigned int ux4 __attribute__((ext_vector_type(4)));

#define DEV __device__ __forceinline__
#define ALPHA 0.18033688011112042f   // 1/sqrt(64) * log2(e), folded into Q at RoPE

DEV void load_lds16(const void* g, void* l) {
  __builtin_amdgcn_global_load_lds(
      (const __attribute__((address_space(1))) unsigned int*)g,
      (__attribute__((address_space(3))) unsigned int*)l, 16, 0, 0);
}

DEV unsigned short f2bf(float f) {
  unsigned int x = __builtin_bit_cast(unsigned int, f);
  unsigned int r = (x + 0x7fffu + ((x >> 16) & 1u)) >> 16;
  return (unsigned short)r;
}
DEV float bf2f(unsigned short u) {
  unsigned int x = ((unsigned int)u) << 16;
  return __builtin_bit_cast(float, x);
}
DEV float exp2_fast(float x) { float r; asm("v_exp_f32 %0, %1" : "=v"(r) : "v"(x)); return r; }
DEV unsigned cvtpk(float lo, float hi) {
  unsigned r; asm("v_cvt_pk_bf16_f32 %0, %1, %2" : "=v"(r) : "v"(lo), "v"(hi)); return r;
}

// ---------------- conversions ----------------

__global__ __launch_bounds__(256) void cvt_x_kernel(const float* __restrict__ x,
                                                    unsigned short* __restrict__ out) {
  int i = (blockIdx.x * 256 + threadIdx.x) * 8;
  fx4 a = *(const fx4*)(x + i);
  fx4 b = *(const fx4*)(x + i + 4);
  bfx8 r;
  r[0] = (short)f2bf(a[0]); r[1] = (short)f2bf(a[1]);
  r[2] = (short)f2bf(a[2]); r[3] = (short)f2bf(a[3]);
  r[4] = (short)f2bf(b[0]); r[5] = (short)f2bf(b[1]);
  r[6] = (short)f2bf(b[2]); r[7] = (short)f2bf(b[3]);
  *(bfx8*)(out + i) = r;
}

__global__ __launch_bounds__(256) void build_wqkvT_kernel(const float* __restrict__ wq,
                                                          const float* __restrict__ wk,
                                                          const float* __restrict__ wv,
                                                          unsigned short* __restrict__ out) {
  int tid = blockIdx.x * 256 + threadIdx.x;   // 1536*1024
  int r = tid >> 10, c = tid & 1023;
  float v;
  if (r < 1024)      v = wq[(size_t)c * 1024 + r];
  else if (r < 1280) v = wk[(size_t)c * 256 + (r - 1024)];
  else               v = wv[(size_t)c * 256 + (r - 1280)];
  out[tid] = f2bf(v);
}

__global__ __launch_bounds__(256) void build_woT_kernel(const float* __restrict__ wo,
                                                        unsigned short* __restrict__ out) {
  int tid = blockIdx.x * 256 + threadIdx.x;   // 1024*1024
  int r = tid >> 10, c = tid & 1023;
  out[tid] = f2bf(wo[(size_t)c * 1024 + r]);
}

// ---------------- RoPE (in place; q-heads pre-scaled by ALPHA) ----------------

__global__ __launch_bounds__(256) void rope_kernel(unsigned short* __restrict__ qkv,
                                                   const float* __restrict__ ct,
                                                   const float* __restrict__ st) {
  int tid = blockIdx.x * 256 + threadIdx.x;   // 4096 * 640
  int row = tid / 640;
  int rem = tid - row * 640;
  int head = rem >> 5, d = rem & 31;          // head 0..19 (16 q then 4 k), d 0..31
  int s = row & 2047;
  float c = ct[s * 64 + d], sn = st[s * 64 + d];
  float sc = (head < 16) ? ALPHA : 1.0f;
  unsigned short* p = qkv + (size_t)row * 1536 + head * 64 + d;
  float x0 = bf2f(p[0]);
  float x1 = bf2f(p[32]);
  p[0]  = f2bf((x0 * c - x1 * sn) * sc);
  p[32] = f2bf((x1 * c + x0 * sn) * sc);
}

// ---------------- GEMM: C[M][ldc] = A[M][K] * Bt[N][K]^T ----------------

template <bool OUT_BF16>
__global__ __launch_bounds__(256) void gemm_bt_kernel(const unsigned short* __restrict__ A,
                                                      const unsigned short* __restrict__ Bt,
                                                      void* __restrict__ Cp,
                                                      int M, int N, int K, int ldc) {
  __shared__ __align__(16) unsigned short As[128 * 32];
  __shared__ __align__(16) unsigned short Bs[128 * 32];
  const int t = threadIdx.x;
  const int l = t & 63;
  const int w = t >> 6;
  const int wm = (w >> 1) * 64, wn = (w & 1) * 64;
  const int bm = blockIdx.x, bn = blockIdx.y;
  fx4 acc[4][4] = {};

  const int ra = t >> 2;
  const int ca = t & 3;

  for (int kt = 0; kt < K; kt += 32) {
    __syncthreads();
#pragma unroll
    for (int p = 0; p < 2; ++p) {
      int rr = ra + p * 64;
      int gca = ((ca ^ ((rr >> 1) & 3)) * 8);
      load_lds16(A + (size_t)(bm * 128 + rr) * K + kt + gca, (char*)As + p * 4096 + t * 16);
      load_lds16(Bt + (size_t)(bn * 128 + rr) * K + kt + gca, (char*)Bs + p * 4096 + t * 16);
    }
    __syncthreads();

    bfx8 af[4], bfr[4];
#pragma unroll
    for (int mi = 0; mi < 4; ++mi) {
      int row = wm + mi * 16 + (l & 15);
      int ch = (l >> 4) ^ ((row >> 1) & 3);
      af[mi] = *(const bfx8*)(As + row * 32 + ch * 8);
      int rowb = wn + mi * 16 + (l & 15);
      int chb = (l >> 4) ^ ((rowb >> 1) & 3);
      bfr[mi] = *(const bfx8*)(Bs + rowb * 32 + chb * 8);
    }
#pragma unroll
    for (int mi = 0; mi < 4; ++mi)
#pragma unroll
      for (int ni = 0; ni < 4; ++ni)
        acc[mi][ni] = __builtin_amdgcn_mfma_f32_16x16x32_bf16(af[mi], bfr[ni], acc[mi][ni], 0, 0, 0);
  }

#pragma unroll
  for (int mi = 0; mi < 4; ++mi) {
    int row0 = bm * 128 + wm + mi * 16 + (l >> 4) * 4;
#pragma unroll
    for (int ni = 0; ni < 4; ++ni) {
      int col = bn * 128 + wn + ni * 16 + (l & 15);
#pragma unroll
      for (int r = 0; r < 4; ++r) {
        if (OUT_BF16)
          ((unsigned short*)Cp)[(size_t)(row0 + r) * ldc + col] = f2bf(acc[mi][ni][r]);
        else
          ((float*)Cp)[(size_t)(row0 + r) * ldc + col] = acc[mi][ni][r];
      }
    }
  }
}

// ---------------- flash attention (causal, GQA) — swapped-operand 32x32 ----------------
// grid (32, 16, 2), 128 threads = 2 waves. Tile T = 31-bx owns q rows T*64..+63;
// wave wv owns rows +32*wv..+31. Swapped QK^T (S^T = K*Q) and swapped PV (O^T = V^T*P^T):
// lane's q = l&31 for both stats and output columns -> all softmax state lane-local.
// KVBLK=64, double-buffered K (chunk-XOR swizzle via pre-swizzled global src) and
// V^T (row-permute pr = d^((d>>3)&7), stride 72) LDS, one barrier per iteration.

__global__ __launch_bounds__(128) void attn_kernel(const unsigned short* __restrict__ qkv,
                                                   unsigned short* __restrict__ out) {
  __shared__ __align__(16) unsigned short Klds[2][64 * 64];  // [buf][row*64 el], 8KB each
  __shared__ __align__(16) unsigned short Vt[2][64 * 72];    // [buf][pr*72 + j], 9KB each

  const int bx = blockIdx.x, head = blockIdx.y, b = blockIdx.z;
  const int T = 31 - bx;                 // big tiles dispatch first (load balance)
  const int kvh = head >> 2;
  const int t = threadIdx.x, wv = t >> 6, l = t & 63;
  const int q5 = l & 31, h = l >> 5;
  const size_t bbase = (size_t)b * 2048;
  const unsigned short* base = qkv + bbase * 1536;
  const int qloc = wv * 32 + q5;         // local q row within 64-tile
  const int qg = T * 64 + qloc;          // seq row

  // Q fragments (B-operand: col=q5, d = dd*16 + h*8 + 0..7). ALPHA pre-applied in rope.
  bfx8 qf[4];
#pragma unroll
  for (int dd = 0; dd < 4; ++dd)
    qf[dd] = *(const bfx8*)(base + (size_t)qg * 1536 + head * 64 + dd * 16 + h * 8);

  fx16 o[2] = {};
  float mrun = -1e30f, lrun = 0.f;
  const int nkb = T + 1;

  // ---- prologue: stage kb=0 into buf 0 ----
#pragma unroll
  for (int p = 0; p < 4; ++p) {
    int idx = p * 128 + t, jj = idx >> 3, c = idx & 7;
    int gc = (c ^ (jj & 7)) * 8;   // pre-swizzled global chunk; LDS stays linear
    load_lds16(base + (size_t)jj * 1536 + 1024 + kvh * 64 + gc, (char*)&Klds[0][0] + idx * 16);
  }
  {
    int vj = t >> 1, vd0 = (t & 1) * 32;
    bfx8 pv0[4];
#pragma unroll
    for (int u = 0; u < 4; ++u)
      pv0[u] = *(const bfx8*)(base + (size_t)vj * 1536 + 1280 + kvh * 64 + vd0 + u * 8);
#pragma unroll
    for (int u = 0; u < 4; ++u)
#pragma unroll
      for (int ii = 0; ii < 8; ++ii) {
        int d = vd0 + u * 8 + ii, pr = d ^ ((d >> 3) & 7);
        Vt[0][pr * 72 + vj] = (unsigned short)pv0[u][ii];
      }
  }
  __syncthreads();

  for (int kb = 0; kb < nkb; ++kb) {
    const int cur = kb & 1, nxt = cur ^ 1;
    const int j0n = (kb + 1) * 64;       // next tile's key base
    const bool stage = (kb + 1 < nkb);
    bfx8 vstage[4];
    if (stage) {
      // K: async global->LDS (drains at this iteration's end barrier)
#pragma unroll
      for (int p = 0; p < 4; ++p) {
        int idx = p * 128 + t, jj = idx >> 3, c = idx & 7;
        int gc = (c ^ (jj & 7)) * 8;
        load_lds16(base + (size_t)(j0n + jj) * 1536 + 1024 + kvh * 64 + gc,
                   (char*)&Klds[nxt][0] + idx * 16);
      }
      // V: issue loads now, LDS-write after softmax (latency hides under compute)
      int vj = t >> 1, vd0 = (t & 1) * 32;
#pragma unroll
      for (int u = 0; u < 4; ++u)
        vstage[u] = *(const bfx8*)(base + (size_t)(j0n + vj) * 1536 + 1280 + kvh * 64 + vd0 + u * 8);
    }

    // ---- QK^T swapped: s[kt] = S^T (rows=keys, cols=q) ----
    fx16 s0 = {}, s1 = {};
#pragma unroll
    for (int dd = 0; dd < 4; ++dd) {
      int slot = ((2 * dd + h) ^ (q5 & 7)) * 16;
      bfx8 kf0 = *(const bfx8*)((const char*)&Klds[cur][0] + q5 * 128 + slot);
      bfx8 kf1 = *(const bfx8*)((const char*)&Klds[cur][0] + (32 + q5) * 128 + slot);
      s0 = __builtin_amdgcn_mfma_f32_32x32x16_bf16(kf0, qf[dd], s0, 0, 0, 0);
      s1 = __builtin_amdgcn_mfma_f32_32x32x16_bf16(kf1, qf[dd], s1, 0, 0, 0);
    }

    // causal mask: only the diagonal 64x64 block needs it (uniform branch)
    if (kb == T) {
#pragma unroll
      for (int r = 0; r < 16; ++r) {
        int klo = (r & 3) + 8 * (r >> 2) + 4 * h;   // C-layout row = local key
        if (klo > qloc) s0[r] = -1e30f;
        if (32 + klo > qloc) s1[r] = -1e30f;
      }
    }

    // ---- online softmax, exp2 domain, all lane-local except 2 shuffles ----
    float mt = s0[0];
#pragma unroll
    for (int r = 1; r < 16; ++r) mt = fmaxf(mt, s0[r]);
#pragma unroll
    for (int r = 0; r < 16; ++r) mt = fmaxf(mt, s1[r]);
    mt = fmaxf(mt, __shfl_xor(mt, 32, 64));
    float mnew = fmaxf(mrun, mt);
    float corr = exp2_fast(mrun - mnew);
    mrun = mnew;
#pragma unroll
    for (int r = 0; r < 16; ++r) { s0[r] = exp2_fast(s0[r] - mnew); s1[r] = exp2_fast(s1[r] - mnew); }
    float lt = 0.f;
#pragma unroll
    for (int r = 0; r < 16; ++r) lt += s0[r] + s1[r];
    lt += __shfl_xor(lt, 32, 64);
    lrun = lrun * corr + lt;

    // pack P to bf16 pairs: U[kt][k8] = (p[2k8], p[2k8+1]) -> keys 8*(k8>>1)+4h+2*(k8&1)+{0,1}
    unsigned U[2][8];
#pragma unroll
    for (int k8 = 0; k8 < 8; ++k8) {
      U[0][k8] = cvtpk(s0[2 * k8], s0[2 * k8 + 1]);
      U[1][k8] = cvtpk(s1[2 * k8], s1[2 * k8 + 1]);
    }
    o[0] *= corr; o[1] *= corr;

    // late V^T write (vstage loads have had QK+softmax to land)
    if (stage) {
      int vj = t >> 1, vd0 = (t & 1) * 32;
#pragma unroll
      for (int u = 0; u < 4; ++u)
#pragma unroll
        for (int ii = 0; ii < 8; ++ii) {
          int d = vd0 + u * 8 + ii, pr = d ^ ((d >> 3) & 7);
          Vt[nxt][pr * 72 + vj] = (unsigned short)vstage[u][ii];
        }
    }

    // ---- PV swapped: o[dt] += V^T-frag * P^T-frag  (output cols = own q) ----
#pragma unroll
    for (int m = 0; m < 4; ++m) {
      const int kt = m >> 1, e = m & 1;
      // B-frag needs keys 16*e(+32*kt) + 8h + {0..7}; exchange halves via shfl_xor(32)
      unsigned vs0 = h ? U[kt][4 * e]     : U[kt][4 * e + 2];
      unsigned vs1 = h ? U[kt][4 * e + 1] : U[kt][4 * e + 3];
      unsigned r0 = (unsigned)__shfl_xor((int)vs0, 32, 64);
      unsigned r1 = (unsigned)__shfl_xor((int)vs1, 32, 64);
      unsigned k0 = h ? U[kt][4 * e + 2] : U[kt][4 * e];
      unsigned k1 = h ? U[kt][4 * e + 3] : U[kt][4 * e + 1];
      ux4 fr;
      fr[0] = h ? r0 : k0; fr[1] = h ? r1 : k1;
      fr[2] = h ? k0 : r0; fr[3] = h ? k1 : r1;
      bfx8 pf = __builtin_bit_cast(bfx8, fr);
#pragma unroll
      for (int dt = 0; dt < 2; ++dt) {
        int d = 32 * dt + q5;
        int pr = d ^ ((d >> 3) & 7);
        bfx8 vf = *(const bfx8*)(&Vt[cur][pr * 72 + 16 * m + 8 * h]);
        o[dt] = __builtin_amdgcn_mfma_f32_32x32x16_bf16(vf, pf, o[dt], 0, 0, 0);
      }
    }
    __syncthreads();
  }

  // ---- epilogue: O^T -> LDS transpose -> coalesced bf16 store ----
  __syncthreads();
  unsigned* Ost = (unsigned*)&Klds[0][0];     // [wave][32 q][33 u32], 8448B
  float inv = 1.0f / lrun;
#pragma unroll
  for (int dt = 0; dt < 2; ++dt)
#pragma unroll
    for (int rp = 0; rp < 8; ++rp) {
      int r = 2 * rp;
      float a = o[dt][r] * inv, bb = o[dt][r + 1] * inv;
      int d = 32 * dt + (r & 3) + 8 * (r >> 2) + 4 * h;   // even, pair (d, d+1)
      Ost[wv * 1056 + q5 * 33 + (d >> 1)] = cvtpk(a, bb);
    }
  __syncthreads();
  {
    int r = t >> 1, hs = t & 1;          // r = local row 0..63
    const unsigned* src = Ost + (r >> 5) * 1056 + (r & 31) * 33 + hs * 16;
    unsigned short* dst = out + (bbase + T * 64 + r) * 1024 + head * 64 + hs * 32;
#pragma unroll
    for (int u = 0; u < 4; ++u) {
      ux4 v4;
      v4[0] = src[4 * u]; v4[1] = src[4 * u + 1]; v4[2] = src[4 * u + 2]; v4[3] = src[4 * u + 3];
      *(ux4*)(dst + u * 8) = v4;
    }
  }
}

// ---------------- launch ----------------

extern "C" void kernel_launch(void* const* d_in, const int* in_sizes, int n_in,
                              void* d_out, int out_size, void* d_ws, size_t ws_size,
                              hipStream_t stream) {
  const float* x    = (const float*)d_in[0];
  const float* cosb = (const float*)d_in[1];
  const float* sinb = (const float*)d_in[2];
  const float* wq   = (const float*)d_in[3];
  const float* wk   = (const float*)d_in[4];
  const float* wv   = (const float*)d_in[5];
  const float* wo   = (const float*)d_in[6];
  float* out = (float*)d_out;

  char* ws = (char*)d_ws;
  unsigned short* xb    = (unsigned short*)ws;                 //  8,388,608 B
  unsigned short* attn  = (unsigned short*)ws;                 //  (alias; xb dead by then)
  unsigned short* wqkvT = (unsigned short*)(ws + 8388608);     //  3,145,728 B
  unsigned short* woT   = (unsigned short*)(ws + 11534336);    //  2,097,152 B
  unsigned short* qkv   = (unsigned short*)(ws + 13631488);    // 12,582,912 B

  cvt_x_kernel<<<2048, 256, 0, stream>>>(x, xb);
  build_wqkvT_kernel<<<6144, 256, 0, stream>>>(wq, wk, wv, wqkvT);
  build_woT_kernel<<<4096, 256, 0, stream>>>(wo, woT);
  gemm_bt_kernel<true><<<dim3(32, 12), 256, 0, stream>>>(xb, wqkvT, qkv, 4096, 1536, 1024, 1536);
  rope_kernel<<<10240, 256, 0, stream>>>(qkv, cosb, sinb);
  attn_kernel<<<dim3(32, 16, 2), 128, 0, stream>>>(qkv, attn);
  gemm_bt_kernel<false><<<dim3(32, 8), 256, 0, stream>>>(attn, woT, out, 4096, 1024, 1024, 1024);
}